// Round 14
// baseline (1195.929 us; speedup 1.0000x reference)
//
#include <hip/hip_runtime.h>

typedef __bf16 bf16;
typedef __bf16 bf16x8 __attribute__((ext_vector_type(8)));
typedef float  f32x4  __attribute__((ext_vector_type(4)));
typedef int    i32x4  __attribute__((ext_vector_type(4)));

#define T_STEPS 128
#define BATCH   256
#define HD      1024
#define N4H     4096
#define EMB_D   128

// MFMA with A-operand pinned in AGPRs (weights), B and acc in VGPRs.
#define MFMA_BF16(acc, Aop, Bop) \
    asm("v_mfma_f32_16x16x32_bf16 %0, %1, %2, %0" : "+v"(acc) : "a"(Aop), "v"(Bop))

// B-gather: direct L2 -> VGPR, literal offset, device-fresh (sc0).
#define GA(i, OFF) asm volatile("global_load_dwordx4 %0, %1, off offset:" OFF " sc0" \
                                : "=v"(bb[i]) : "v"(gsrc));
// Consume gather i: literal vmcnt wait (in-order loads), then 2 MFMAs.
// "+v"(bb[i]) makes the MFMA operand depend on the waitcnt asm (rule-#18 fence).
#define CO(i, VM, AO, AX) \
    asm volatile("s_waitcnt vmcnt(" VM ")" : "+v"(bb[i]) :: "memory"); \
    MFMA_BF16(AO, ArO[i], bb[i]); \
    MFMA_BF16(AX, ArX[i], bb[i]);

__device__ __forceinline__ float fast_sigmoid(float x) {
    return 1.0f / (1.0f + __expf(-x));
}
__device__ __forceinline__ float fast_tanh(float x) {
    return 1.0f - 2.0f / (__expf(2.0f * x) + 1.0f);
}

// ---------------- prep: P[v][n] = (emb[v] @ Wx_gate)[hcol] + b_gate[hcol],
// n = 4*hcol + gate, gate order (g,i,f,o) ----------------
__global__ void build_P(const float* __restrict__ emb,
                        const float* __restrict__ Wgx, const float* __restrict__ Wix,
                        const float* __restrict__ Wfx, const float* __restrict__ Wox,
                        const float* __restrict__ bg,  const float* __restrict__ bi,
                        const float* __restrict__ bfv, const float* __restrict__ bo,
                        float* __restrict__ P)
{
    int n = blockIdx.x * 256 + threadIdx.x;
    int v  = n >> 12;
    int nn = n & (N4H - 1);
    int hcol = nn >> 2, gate = nn & 3;
    const float* Wx = (gate == 0) ? Wgx : (gate == 1) ? Wix : (gate == 2) ? Wfx : Wox;
    const float* bb = (gate == 0) ? bg  : (gate == 1) ? bi  : (gate == 2) ? bfv : bo;
    float s = bb[hcol];
    for (int e = 0; e < EMB_D; ++e)
        s += emb[v * EMB_D + e] * Wx[e * HD + hcol];
    P[n] = s;
}

// ---------------- prep: WhpT[n][k] = Wh_gate[k][hcol] as bf16 ----------------
__global__ void build_W(const float* __restrict__ Wgh, const float* __restrict__ Wih,
                        const float* __restrict__ Wfh, const float* __restrict__ Woh,
                        bf16* __restrict__ WhpT)
{
    __shared__ float tile[64][65];
    int bid  = blockIdx.x;
    int gate = bid >> 8;
    int t2   = bid & 255;
    int kt = t2 >> 4, ht = t2 & 15;
    const float* W = (gate == 0) ? Wgh : (gate == 1) ? Wih : (gate == 2) ? Wfh : Woh;
    int tid = threadIdx.x;
    #pragma unroll
    for (int it = 0; it < 16; ++it) {
        int idx = it * 256 + tid;
        int kk = idx >> 6, hh = idx & 63;
        tile[kk][hh] = W[(size_t)(kt * 64 + kk) * HD + ht * 64 + hh];
    }
    __syncthreads();
    #pragma unroll
    for (int it = 0; it < 16; ++it) {
        int idx = it * 256 + tid;
        int hh = idx >> 6, kk = idx & 63;
        int n = (ht * 64 + hh) * 4 + gate;
        WhpT[(size_t)n * HD + kt * 64 + kk] = (bf16)tile[kk][hh];
    }
}

// ---------------- main persistent kernel ----------------
// 256 blocks x 512 threads, 1 block/CU (LDS pad forces it; coop launch ->
// exactly 32 blocks/XCD). Group g = physical XCD; member j = election ticket.
// TWO-PHASE cohort interleave: phase A = rows [g*32,+16), phase B = rows
// [g*32+16,+32), independent barrier chains ctrA/ctrB -> each phase's
// arrivals are one full phase older when polled (discovery latency hidden),
// plus early pre-polls. B operand: NO LDS - direct per-lane L2 gather
// (16x global_load_dwordx4 sc0, literal offsets) software-pipelined with
// literal vmcnt against 4 independent MFMA acc chains. Weights in AGPRs.
// Wave (w,kh) owns fn=kh, ships other-fn partials to partner (wid^4) via
// stride-9 LDS. Safety: poll ALL 32 producers (arrival is post-read).
__global__ __launch_bounds__(512, 2)
void lstm_main(const int* __restrict__ x, const float* __restrict__ P,
               const bf16* __restrict__ WhpT, bf16* __restrict__ hbuf,
               int* __restrict__ ctl)
{
    __shared__ float red[8][64][9];      // 18 KB exchange (stride 9, conflict-free)
    __shared__ bf16  hst[16][34];        // 1.1 KB h-out packing stage (per phase)
    __shared__ int   sj;
    __shared__ char  pad[65536];         // occupancy pad: forces 1 block/CU

    const int tid  = threadIdx.x;
    const int lane = tid & 63;
    const int wid  = tid >> 6;           // 0..7
    const int w    = wid & 3;            // n-subgroup (32 gate-cols)
    const int kh   = wid >> 2;           // k-half; also the OWNED fn
    const int frow = lane & 15;
    const int kgrp = lane >> 4;

    // keep pad alive (never executes; blockDim.y==1 at runtime)
    if (blockDim.y == 2) pad[tid] = 1;

    // ---- XCD-local group election (agent-scope ticket, runs once) ----
    int xcc;
    asm("s_getreg_b32 %0, hwreg(HW_REG_XCC_ID)" : "=s"(xcc));
    const int g = xcc & 7;
    if (tid == 0)
        sj = __hip_atomic_fetch_add(ctl + 1024 + g * 16, 1,
                                    __ATOMIC_RELAXED, __HIP_MEMORY_SCOPE_AGENT) & 31;
    __syncthreads();
    const int j = sj;
    int* ctrA = ctl + (g * 2 + 0) * 32;  // 32 per-block counters, phase A
    int* ctrB = ctl + (g * 2 + 1) * 32;  // phase B
    const int* slotA = ctrA + (lane & 31);
    const int* slotB = ctrB + (lane & 31);

    // ---- persistent A in AGPRs, split owned-fn / other-fn (same as r8) ----
    const int rowO = j * 128 + w * 32 + kh * 16 + frow;
    const int rowX = j * 128 + w * 32 + (1 - kh) * 16 + frow;
    const bf16* AbO = WhpT + (size_t)rowO * HD + kh * 512 + kgrp * 8;
    const bf16* AbX = WhpT + (size_t)rowX * HD + kh * 512 + kgrp * 8;
    i32x4 ArO[16], ArX[16];
    #pragma unroll
    for (int ks = 0; ks < 16; ++ks) {
        ArO[ks] = *(const i32x4*)(const void*)(AbO + ks * 32);
        ArX[ks] = *(const i32x4*)(const void*)(AbX + ks * 32);
    }
    #pragma unroll
    for (int ks = 0; ks < 16; ++ks)
        asm volatile("" : "+a"(ArO[ks]), "+a"(ArX[ks]));

    const int clc = w * 8 + kh * 4 + kgrp;       // owned local h col (0..31)
    const int pnb = j * 128 + clc * 4;           // owned-fn P base
    const int mrA = g * 32 + frow;               // phase-A batch row
    const int mrB = g * 32 + 16 + frow;          // phase-B batch row
    float* rw = &red[0][0][0] + ((size_t)(wid ^ 4) * 64 + lane) * 9;
    const float* rr = &red[0][0][0] + ((size_t)wid * 64 + lane) * 9;

    float stA = 0.f, stB = 0.f;
    f32x4 accPA, accPB;
    { int xv = x[mrA]; accPA = *(const f32x4*)(P + (size_t)xv * N4H + pnb); }
    { int xv = x[mrB]; accPB = *(const f32x4*)(P + (size_t)xv * N4H + pnb); }
    int cvPreA = 0, cvPreB = 0;

    auto phase = [&](int t, int p, const int* slot, int* ctr, const int* slotOther,
                     f32x4& accP, float& st, int mr, int& cvPreSelf, int& cvPreOther)
    {
        f32x4 z = {0.f, 0.f, 0.f, 0.f};
        f32x4 accOa = accP, accOb = z, accXa = z, accXb = z;

        if (t > 0) {
            if (!__all(cvPreSelf >= t)) {          // pre-poll miss -> spin
                int cv; long guard = 0;
                do {
                    cv = __hip_atomic_load(slot, __ATOMIC_RELAXED,
                                           __HIP_MEMORY_SCOPE_AGENT);
                } while (!__all(cv >= t) && ++guard < (1L << 17));
            }
            const bf16* gp = hbuf + (size_t)(t & 1) * BATCH * HD
                                  + (size_t)mr * HD + kh * 512 + kgrp * 8;
            const char* gsrc = (const char*)gp;
            i32x4 bb[16];
            GA(0,"0")   GA(1,"64")  GA(2,"128") GA(3,"192")
            GA(4,"256") GA(5,"320") GA(6,"384") GA(7,"448")
            CO(0,"7",accOa,accXa) CO(1,"6",accOb,accXb)
            CO(2,"5",accOa,accXa) CO(3,"4",accOb,accXb)
            GA(8,"512") GA(9,"576") GA(10,"640") GA(11,"704")
            CO(4,"7",accOa,accXa) CO(5,"6",accOb,accXb)
            CO(6,"5",accOa,accXa) CO(7,"4",accOb,accXb)
            GA(12,"768") GA(13,"832") GA(14,"896") GA(15,"960")
            CO(8,"7",accOa,accXa)  CO(9,"6",accOb,accXb)
            CO(10,"5",accOa,accXa) CO(11,"4",accOb,accXb)
            CO(12,"3",accOa,accXa) CO(13,"2",accOb,accXb)
            CO(14,"1",accOa,accXa) CO(15,"0",accOb,accXb)
        }
        f32x4 accO = accOa + accOb;
        f32x4 accX = accXa + accXb;

        // ---- ship other-fn partials to partner wave ----
        rw[0] = accX[0]; rw[1] = accX[1]; rw[2] = accX[2]; rw[3] = accX[3];
        __syncthreads();                                   // (1) exchange
        accO[0] += rr[0]; accO[1] += rr[1]; accO[2] += rr[2]; accO[3] += rr[3];

        // pre-poll the OTHER phase's counters (hides IF load latency)
        cvPreOther = __hip_atomic_load(slotOther, __ATOMIC_RELAXED,
                                       __HIP_MEMORY_SCOPE_AGENT);

        // ---- gates + state update (lane-local) ----
        {
            float gg = fast_tanh(accO[0]);
            float ii = fast_sigmoid(accO[1]);
            float ff = fast_sigmoid(accO[2]);
            float oo = fast_sigmoid(accO[3]);
            float s = gg * ii + st * ff;
            st = s;
            hst[frow][clc] = (bf16)(fast_tanh(s) * oo);
        }
        // prefetch next step's x/P for this phase
        if (t < T_STEPS - 1) {
            int xv = x[(t + 1) * BATCH + mr];
            accP = *(const f32x4*)(P + (size_t)xv * N4H + pnb);
        }
        __syncthreads();                                   // (2) hst ready
        if (tid < 256) {
            bf16* hout = hbuf + (size_t)((t + 1) & 1) * BATCH * HD;
            int r = tid >> 4, cp = (tid & 15) * 2;
            unsigned lo = (unsigned)__builtin_bit_cast(unsigned short, hst[r][cp]);
            unsigned hi = (unsigned)__builtin_bit_cast(unsigned short, hst[r][cp + 1]);
            unsigned pv = lo | (hi << 16);
            *(unsigned*)(hout + (size_t)(g * 32 + p * 16 + r) * HD + j * 32 + cp) = pv;
        }
        __syncthreads();                                   // (3) drain h stores
        if (tid == 0 && t < T_STEPS - 1)
            __hip_atomic_store(ctr + j, t + 1,
                               __ATOMIC_RELAXED, __HIP_MEMORY_SCOPE_AGENT);
    };

    for (int t = 0; t < T_STEPS; ++t) {
        phase(t, 0, slotA, ctrA, slotB, accPA, stA, mrA, cvPreA, cvPreB);
        phase(t, 1, slotB, ctrB, slotA, accPB, stB, mrB, cvPreB, cvPreA);
    }
}

// ---------------- final projection: out[b][c] = h_T[b] @ Wph + bp ----------------
__global__ void proj_out(const bf16* __restrict__ h, const float* __restrict__ Wph,
                         const float* __restrict__ bp, float* __restrict__ out)
{
    __shared__ float red[256][10];
    int b = blockIdx.x, tid = threadIdx.x;
    float acc[10];
    #pragma unroll
    for (int c = 0; c < 10; ++c) acc[c] = 0.f;
    for (int k = tid; k < HD; k += 256) {
        float hv = (float)h[(size_t)b * HD + k];
        #pragma unroll
        for (int c = 0; c < 10; ++c)
            acc[c] += hv * Wph[k * 10 + c];
    }
    #pragma unroll
    for (int c = 0; c < 10; ++c) red[tid][c] = acc[c];
    __syncthreads();
    for (int s = 128; s > 0; s >>= 1) {
        if (tid < s) {
            #pragma unroll
            for (int c = 0; c < 10; ++c) red[tid][c] += red[tid + s][c];
        }
        __syncthreads();
    }
    if (tid < 10) out[b * 10 + tid] = red[0][tid] + bp[tid];
}

extern "C" void kernel_launch(void* const* d_in, const int* in_sizes, int n_in,
                              void* d_out, int out_size, void* d_ws, size_t ws_size,
                              hipStream_t stream)
{
    const int*   x   = (const int*)  d_in[0];
    const float* emb = (const float*)d_in[1];
    const float* Wgx = (const float*)d_in[2];
    const float* Wgh = (const float*)d_in[3];
    const float* Wix = (const float*)d_in[4];
    const float* Wih = (const float*)d_in[5];
    const float* Wfx = (const float*)d_in[6];
    const float* Wfh = (const float*)d_in[7];
    const float* Wox = (const float*)d_in[8];
    const float* Woh = (const float*)d_in[9];
    const float* bg  = (const float*)d_in[10];
    const float* bi  = (const float*)d_in[11];
    const float* bfv = (const float*)d_in[12];
    const float* bo  = (const float*)d_in[13];
    const float* Wph = (const float*)d_in[14];
    const float* bp  = (const float*)d_in[15];

    char* ws = (char*)d_ws;
    bf16*  WhpT = (bf16*)ws;                                   // 8 MB
    float* P    = (float*)(ws + 8388608);                      // 160 KB
    bf16*  hbuf = (bf16*)(ws + 8388608 + 163840);              // 2 x 512 KB
    int*   ctl  = (int*)(ws + 8388608 + 163840 + 1048576);     // ctrA/B[8x32] + election

    hipMemsetAsync(ctl, 0, 8192, stream);                      // covers ctrs + election
    build_P<<<160, 256, 0, stream>>>(emb, Wgx, Wix, Wfx, Wox, bg, bi, bfv, bo, P);
    build_W<<<1024, 256, 0, stream>>>(Wgh, Wih, Wfh, Woh, WhpT);

    void* args[] = { (void*)&x, (void*)&P, (void*)&WhpT, (void*)&hbuf, (void*)&ctl };
    hipLaunchCooperativeKernel((void*)lstm_main, dim3(256), dim3(512), args, 0, stream);

    proj_out<<<256, 256, 0, stream>>>(hbuf, Wph, bp, (float*)d_out);
}